// Round 1
// baseline (982.447 us; speedup 1.0000x reference)
//
#include <hip/hip_runtime.h>
#include <math.h>

#define EPSF 1e-8f

__device__ __forceinline__ float sigf(float x) { return 1.0f / (1.0f + expf(-x)); }
__device__ __forceinline__ float softplusf(float x) { return x > 20.0f ? x : log1pf(expf(x)); }

// ---------------- pack X = [in_data(64) | prev_reads(4x64) | h0(512)] : [256][832]
__global__ void pack_x_kernel(const float* __restrict__ in_data,
                              const float* __restrict__ prev_reads,
                              const float* __restrict__ h0,
                              float* __restrict__ X) {
  int idx = blockIdx.x * 256 + threadIdx.x;
  if (idx >= 256 * 832) return;
  int b = idx / 832, t = idx % 832;
  float v;
  if (t < 64) v = in_data[b * 64 + t];
  else if (t < 320) { int i = (t - 64) >> 6, m = (t - 64) & 63; v = prev_reads[((size_t)i * 256 + b) * 64 + m]; }
  else v = h0[b * 512 + (t - 320)];
  X[idx] = v;
}

// ---------------- gates = X @ [W_ih|W_hh]^T + b_ih + b_hh : [256][2048]
__global__ __launch_bounds__(256) void gemm_gates_kernel(
    const float* __restrict__ X, const float* __restrict__ W_ih,
    const float* __restrict__ W_hh, const float* __restrict__ b_ih,
    const float* __restrict__ b_hh, float* __restrict__ gates) {
  __shared__ float As[16][33];
  __shared__ float Ws[16][65];
  int tid = threadIdx.x, tx = tid & 15, ty = tid >> 4;
  int row0 = blockIdx.y * 32, col0 = blockIdx.x * 64;
  float acc[2][4] = {{0,0,0,0},{0,0,0,0}};
  for (int k0 = 0; k0 < 832; k0 += 16) {
    const float* Wp; int kw, KW;
    if (k0 < 320) { Wp = W_ih; kw = k0; KW = 320; }
    else          { Wp = W_hh; kw = k0 - 320; KW = 512; }
    for (int i = tid; i < 32 * 16; i += 256) {
      int rr = i >> 4, cc = i & 15;
      As[cc][rr] = X[(size_t)(row0 + rr) * 832 + k0 + cc];
    }
    for (int i = tid; i < 64 * 16; i += 256) {
      int rr = i >> 4, cc = i & 15;
      Ws[cc][rr] = Wp[(size_t)(col0 + rr) * KW + kw + cc];
    }
    __syncthreads();
#pragma unroll
    for (int kk = 0; kk < 16; kk++) {
      float a0 = As[kk][ty * 2 + 0], a1 = As[kk][ty * 2 + 1];
      float w0 = Ws[kk][tx * 4 + 0], w1 = Ws[kk][tx * 4 + 1];
      float w2 = Ws[kk][tx * 4 + 2], w3 = Ws[kk][tx * 4 + 3];
      acc[0][0] += a0 * w0; acc[0][1] += a0 * w1; acc[0][2] += a0 * w2; acc[0][3] += a0 * w3;
      acc[1][0] += a1 * w0; acc[1][1] += a1 * w1; acc[1][2] += a1 * w2; acc[1][3] += a1 * w3;
    }
    __syncthreads();
  }
  for (int i = 0; i < 2; i++)
    for (int j = 0; j < 4; j++) {
      int cc = col0 + tx * 4 + j;
      gates[(size_t)(row0 + ty * 2 + i) * 2048 + cc] = acc[i][j] + b_ih[cc] + b_hh[cc];
    }
}

// ---------------- LSTM elementwise: c,h
__global__ void lstm_elem_kernel(const float* __restrict__ gates,
                                 const float* __restrict__ c0,
                                 float* __restrict__ c, float* __restrict__ h) {
  int idx = blockIdx.x * 256 + threadIdx.x;
  if (idx >= 256 * 512) return;
  int b = idx >> 9, u = idx & 511;
  const float* g = gates + (size_t)b * 2048;
  float ig = sigf(g[u]), fg = sigf(g[512 + u]);
  float gg = tanhf(g[1024 + u]), og = sigf(g[1536 + u]);
  float cv = fg * c0[idx] + ig * gg;
  c[idx] = cv;
  h[idx] = og * tanhf(cv);
}

// ---------------- p_raw = c @ [W_addr(560)|W_ea(512)]^T + bias : [256][1072]
__global__ __launch_bounds__(256) void gemm_heads_kernel(
    const float* __restrict__ C, const float* __restrict__ W_addr,
    const float* __restrict__ W_ea, const float* __restrict__ b_addr,
    const float* __restrict__ b_ea, float* __restrict__ p_raw) {
  __shared__ float As[16][33];
  __shared__ float Ws[16][65];
  int tid = threadIdx.x, tx = tid & 15, ty = tid >> 4;
  int row0 = blockIdx.y * 32, col0 = blockIdx.x * 64;
  float acc[2][4] = {{0,0,0,0},{0,0,0,0}};
  for (int k0 = 0; k0 < 512; k0 += 16) {
    for (int i = tid; i < 32 * 16; i += 256) {
      int rr = i >> 4, cc = i & 15;
      As[cc][rr] = C[(size_t)(row0 + rr) * 512 + k0 + cc];
    }
    for (int i = tid; i < 64 * 16; i += 256) {
      int rr = i >> 4, cc = i & 15;
      int col = col0 + rr;
      float v = 0.f;
      if (col < 560) v = W_addr[(size_t)col * 512 + k0 + cc];
      else if (col < 1072) v = W_ea[(size_t)(col - 560) * 512 + k0 + cc];
      Ws[cc][rr] = v;
    }
    __syncthreads();
#pragma unroll
    for (int kk = 0; kk < 16; kk++) {
      float a0 = As[kk][ty * 2 + 0], a1 = As[kk][ty * 2 + 1];
      float w0 = Ws[kk][tx * 4 + 0], w1 = Ws[kk][tx * 4 + 1];
      float w2 = Ws[kk][tx * 4 + 2], w3 = Ws[kk][tx * 4 + 3];
      acc[0][0] += a0 * w0; acc[0][1] += a0 * w1; acc[0][2] += a0 * w2; acc[0][3] += a0 * w3;
      acc[1][0] += a1 * w0; acc[1][1] += a1 * w1; acc[1][2] += a1 * w2; acc[1][3] += a1 * w3;
    }
    __syncthreads();
  }
  for (int i = 0; i < 2; i++)
    for (int j = 0; j < 4; j++) {
      int col = col0 + tx * 4 + j;
      if (col < 1072) {
        float bias = col < 560 ? b_addr[col] : b_ea[col - 560];
        p_raw[(size_t)(row0 + ty * 2 + i) * 1072 + col] = acc[i][j] + bias;
      }
    }
}

// ---------------- unpack head params: k(tanh)+knorm, beta, gate, s(softmax3), gamma, e(sig), a(tanh)
__global__ void head_params_kernel(const float* __restrict__ p_raw,
    float* __restrict__ kvec, float* __restrict__ knorm,
    float* __restrict__ betav, float* __restrict__ gatev,
    float* __restrict__ sv, float* __restrict__ gammav,
    float* __restrict__ evec, float* __restrict__ avec) {
  int hi = blockIdx.x, b = blockIdx.y, t = threadIdx.x;
  const float* p = p_raw + (size_t)b * 1072 + hi * 70;
  if (t < 64) {
    float kvv = tanhf(p[t]);
    kvec[((size_t)hi * 256 + b) * 64 + t] = kvv;
    float s = kvv * kvv;
    for (int m = 1; m < 64; m <<= 1) s += __shfl_xor(s, m);
    if (t == 0) {
      int hb = hi * 256 + b;
      knorm[hb] = sqrtf(s);
      betav[hb] = softplusf(p[64]);
      gatev[hb] = sigf(p[65]);
      float a0 = p[66], a1 = p[67], a2 = p[68];
      float mm = fmaxf(a0, fmaxf(a1, a2));
      float e0 = expf(a0 - mm), e1 = expf(a1 - mm), e2 = expf(a2 - mm);
      float es = e0 + e1 + e2;
      sv[hb * 3 + 0] = e0 / es; sv[hb * 3 + 1] = e1 / es; sv[hb * 3 + 2] = e2 / es;
      gammav[hb] = 1.0f + softplusf(p[69]);
    }
  } else if ((hi & 1) && hi < 7) {      // write heads 1,3,5 -> e/a slots 0,1,2 (head 7 is dead)
    int wj = hi >> 1, t2 = t - 64;
    const float* ea = p_raw + (size_t)b * 1072 + 560 + wj * 128;
    evec[((size_t)wj * 256 + b) * 64 + t2] = sigf(ea[t2]);
    avec[((size_t)wj * 256 + b) * 64 + t2] = tanhf(ea[64 + t2]);
  }
}

// ---------------- the memory pass: streams pristine mem0, applies NW writes in registers,
// computes up to 2 key dots + row norm on the final stage, accumulates one weighted read.
// lane mapping: lane = r*16+q; q -> m-quad (float4 q of 16), r -> row within 4-row group.
// A wave-instruction reads 1 KB fully contiguous (4 rows x 256 B).
template<int NW, int NKEYS, int READ_MODE> // READ_MODE 0:none 1:penultimate stage 2:final stage
__global__ __launch_bounds__(256) void pass_kernel(
    const float* __restrict__ mem, const float* __restrict__ kvec,
    int keyA, int keyB, const float* __restrict__ w_all,
    const float* __restrict__ evec, const float* __restrict__ avec,
    int rw_head, float* __restrict__ dot_a, float* __restrict__ dot_b,
    float* __restrict__ normr, float* __restrict__ read_out) {
  const int BB = 256, NN = 4096;
  int b = blockIdx.y;
  int n0 = blockIdx.x * 256;
  int tid = threadIdx.x;
  int wv = tid >> 6, lane = tid & 63;
  int q = lane & 15, r = lane >> 4;
  size_t bo = (size_t)b * NN;

  float4 kA = make_float4(0,0,0,0), kB = make_float4(0,0,0,0);
  if (NKEYS >= 1) kA = *(const float4*)(kvec + ((size_t)keyA * BB + b) * 64 + q * 4);
  if (NKEYS >= 2) kB = *(const float4*)(kvec + ((size_t)keyB * BB + b) * 64 + q * 4);
  float4 ev[3], av[3];
  const float* wrow[3];
  const int whead[3] = {1, 3, 5};
#pragma unroll
  for (int j = 0; j < NW; j++) {
    ev[j] = *(const float4*)(evec + ((size_t)j * BB + b) * 64 + q * 4);
    av[j] = *(const float4*)(avec + ((size_t)j * BB + b) * 64 + q * 4);
    wrow[j] = w_all + ((size_t)whead[j] * BB + b) * NN;
  }
  const float* rwrow = READ_MODE ? (w_all + ((size_t)rw_head * BB + b) * NN) : nullptr;

  __shared__ float sdA[256], sdB[256], snm[256];
  __shared__ float sred[4][16][4];

  const float4* m4 = (const float4*)mem;
  size_t base = (bo + n0 + (size_t)wv * 64) * 16 + lane;

  float rx = 0.f, ry = 0.f, rz = 0.f, rw_ = 0.f;
#pragma unroll 4
  for (int t = 0; t < 16; t++) {
    int nl = wv * 64 + t * 4 + r;
    int n = n0 + nl;
    float4 v = m4[base + (size_t)t * 64];
    float vx = v.x, vy = v.y, vz = v.z, vw = v.w;
#pragma unroll
    for (int j = 0; j < NW; j++) {
      if (READ_MODE == 1 && j == NW - 1) {
        float rwt = rwrow[n];
        rx += rwt * vx; ry += rwt * vy; rz += rwt * vz; rw_ += rwt * vw;
      }
      float wj = wrow[j][n];
      vx = vx * (1.f - wj * ev[j].x) + wj * av[j].x;
      vy = vy * (1.f - wj * ev[j].y) + wj * av[j].y;
      vz = vz * (1.f - wj * ev[j].z) + wj * av[j].z;
      vw = vw * (1.f - wj * ev[j].w) + wj * av[j].w;
    }
    if (READ_MODE == 2) {
      float rwt = rwrow[n];
      rx += rwt * vx; ry += rwt * vy; rz += rwt * vz; rw_ += rwt * vw;
    }
    if (NKEYS >= 1) {
      float dA = vx * kA.x + vy * kA.y + vz * kA.z + vw * kA.w;
      float nm = vx * vx + vy * vy + vz * vz + vw * vw;
      float dB = 0.f;
      if (NKEYS >= 2) dB = vx * kB.x + vy * kB.y + vz * kB.z + vw * kB.w;
#pragma unroll
      for (int m = 1; m < 16; m <<= 1) {
        dA += __shfl_xor(dA, m);
        nm += __shfl_xor(nm, m);
        if (NKEYS >= 2) dB += __shfl_xor(dB, m);
      }
      if (q == 0) {
        sdA[nl] = dA; snm[nl] = sqrtf(nm);
        if (NKEYS >= 2) sdB[nl] = dB;
      }
    }
  }
  if (READ_MODE) {
#pragma unroll
    for (int m = 16; m < 64; m <<= 1) {
      rx += __shfl_xor(rx, m); ry += __shfl_xor(ry, m);
      rz += __shfl_xor(rz, m); rw_ += __shfl_xor(rw_, m);
    }
    if (r == 0) { sred[wv][q][0] = rx; sred[wv][q][1] = ry; sred[wv][q][2] = rz; sred[wv][q][3] = rw_; }
  }
  __syncthreads();
  if (NKEYS >= 1) {
    dot_a[bo + n0 + tid] = sdA[tid];
    normr[bo + n0 + tid] = snm[tid];
    if (NKEYS >= 2) dot_b[bo + n0 + tid] = sdB[tid];
  }
  if (READ_MODE && tid < 64) {
    int qq = tid >> 2, cc = tid & 3;
    float s = sred[0][qq][cc] + sred[1][qq][cc] + sred[2][qq][cc] + sred[3][qq][cc];
    atomicAdd(&read_out[b * 64 + qq * 4 + cc], s);
  }
}

// ---------------- per-head addressing chain: score->softmax->interp->shift->sharpen -> w
__global__ __launch_bounds__(256) void chain_kernel(
    const float* __restrict__ dot_a, const float* __restrict__ dot_b,
    const float* __restrict__ normr, const float* __restrict__ knorm,
    const float* __restrict__ betav, const float* __restrict__ gatev,
    const float* __restrict__ sv, const float* __restrict__ gammav,
    const float* __restrict__ prev_w, float* __restrict__ w_all,
    int head_base) {
  const int NN = 4096, BB = 256;
  int which = blockIdx.x, b = blockIdx.y;
  int head = head_base + which;
  const float* dp = which ? dot_b : dot_a;
  size_t bo = (size_t)b * NN;
  __shared__ float wg[4096];
  __shared__ float redm[4], reds[4], reds2[4];
  int tid = threadIdx.x;
  int lane = tid & 63, wv = tid >> 6;
  int hb = head * BB + b;
  float kn = knorm[hb], be = betav[hb], ga = gatev[hb], gm = gammav[hb];
  float s0 = sv[hb * 3 + 0], s1 = sv[hb * 3 + 1], s2 = sv[hb * 3 + 2];

  float sc[16];
  float mx = -1e30f;
#pragma unroll
  for (int i = 0; i < 16; i++) {
    int n = tid + i * 256;
    float d = dp[bo + n], rn = normr[bo + n];
    sc[i] = be * d / (rn * kn + EPSF);
    mx = fmaxf(mx, sc[i]);
  }
  for (int m = 1; m < 64; m <<= 1) mx = fmaxf(mx, __shfl_xor(mx, m));
  if (lane == 0) redm[wv] = mx;
  __syncthreads();
  mx = fmaxf(fmaxf(redm[0], redm[1]), fmaxf(redm[2], redm[3]));
  float sum = 0.f;
#pragma unroll
  for (int i = 0; i < 16; i++) { sc[i] = expf(sc[i] - mx); sum += sc[i]; }
  for (int m = 1; m < 64; m <<= 1) sum += __shfl_xor(sum, m);
  if (lane == 0) reds[wv] = sum;
  __syncthreads();
  sum = reds[0] + reds[1] + reds[2] + reds[3];
  float inv = 1.0f / sum;
  const float* pw = prev_w + (size_t)head * BB * NN + bo;
#pragma unroll
  for (int i = 0; i < 16; i++) {
    int n = tid + i * 256;
    wg[n] = ga * (sc[i] * inv) + (1.f - ga) * pw[n];
  }
  __syncthreads();
  float wp[16];
  float sum2 = 0.f;
#pragma unroll
  for (int i = 0; i < 16; i++) {
    int n = tid + i * 256;
    float wsv = s0 * wg[(n + NN - 1) & (NN - 1)] + s1 * wg[n] + s2 * wg[(n + 1) & (NN - 1)];
    wp[i] = powf(wsv, gm);
    sum2 += wp[i];
  }
  for (int m = 1; m < 64; m <<= 1) sum2 += __shfl_xor(sum2, m);
  if (lane == 0) reds2[wv] = sum2;
  __syncthreads();
  sum2 = reds2[0] + reds2[1] + reds2[2] + reds2[3];
  float invs = 1.0f / (sum2 + EPSF);
  float* wo = w_all + (size_t)head * BB * NN + bo;
#pragma unroll
  for (int i = 0; i < 16; i++) wo[tid + i * 256] = wp[i] * invs;
}

// ---------------- state = [h | read0 | read2 | read4 | read6] : [256][768]
__global__ void pack_state_kernel(const float* __restrict__ h,
                                  const float* __restrict__ reads,
                                  float* __restrict__ state) {
  int idx = blockIdx.x * 256 + threadIdx.x;
  if (idx >= 256 * 768) return;
  int b = idx / 768, t = idx % 768;
  float v;
  if (t < 512) v = h[b * 512 + t];
  else { int slot = (t - 512) >> 6, m = (t - 512) & 63; v = reads[((size_t)slot * 256 + b) * 64 + m]; }
  state[idx] = v;
}

// ---------------- out = sigmoid(state @ W_out^T + b_out) : [256][64]
__global__ __launch_bounds__(256) void gemm_out_kernel(
    const float* __restrict__ state, const float* __restrict__ W_out,
    const float* __restrict__ b_out, float* __restrict__ out) {
  __shared__ float As[16][33];
  __shared__ float Ws[16][65];
  int tid = threadIdx.x, tx = tid & 15, ty = tid >> 4;
  int row0 = blockIdx.y * 32;
  float acc[2][4] = {{0,0,0,0},{0,0,0,0}};
  for (int k0 = 0; k0 < 768; k0 += 16) {
    for (int i = tid; i < 32 * 16; i += 256) {
      int rr = i >> 4, cc = i & 15;
      As[cc][rr] = state[(size_t)(row0 + rr) * 768 + k0 + cc];
    }
    for (int i = tid; i < 64 * 16; i += 256) {
      int rr = i >> 4, cc = i & 15;
      Ws[cc][rr] = W_out[(size_t)rr * 768 + k0 + cc];
    }
    __syncthreads();
#pragma unroll
    for (int kk = 0; kk < 16; kk++) {
      float a0 = As[kk][ty * 2 + 0], a1 = As[kk][ty * 2 + 1];
      float w0 = Ws[kk][tx * 4 + 0], w1 = Ws[kk][tx * 4 + 1];
      float w2 = Ws[kk][tx * 4 + 2], w3 = Ws[kk][tx * 4 + 3];
      acc[0][0] += a0 * w0; acc[0][1] += a0 * w1; acc[0][2] += a0 * w2; acc[0][3] += a0 * w3;
      acc[1][0] += a1 * w0; acc[1][1] += a1 * w1; acc[1][2] += a1 * w2; acc[1][3] += a1 * w3;
    }
    __syncthreads();
  }
  for (int i = 0; i < 2; i++)
    for (int j = 0; j < 4; j++) {
      int cc = tx * 4 + j;
      out[(size_t)(row0 + ty * 2 + i) * 64 + cc] = sigf(acc[i][j] + b_out[cc]);
    }
}

extern "C" void kernel_launch(void* const* d_in, const int* in_sizes, int n_in,
                              void* d_out, int out_size, void* d_ws, size_t ws_size,
                              hipStream_t stream) {
  const float* in_data = (const float*)d_in[0];
  const float* memory  = (const float*)d_in[1];
  const float* h0      = (const float*)d_in[2];
  const float* c0      = (const float*)d_in[3];
  const float* prev_w  = (const float*)d_in[4];
  const float* prev_r  = (const float*)d_in[5];
  const float* W_ih    = (const float*)d_in[6];
  const float* b_ih    = (const float*)d_in[7];
  const float* W_hh    = (const float*)d_in[8];
  const float* b_hh    = (const float*)d_in[9];
  const float* W_out   = (const float*)d_in[10];
  const float* b_out   = (const float*)d_in[11];
  const float* W_addr  = (const float*)d_in[12];
  const float* b_addr  = (const float*)d_in[13];
  const float* W_ea    = (const float*)d_in[14];
  const float* b_ea    = (const float*)d_in[15];
  float* out = (float*)d_out;
  (void)in_sizes; (void)n_in; (void)out_size; (void)ws_size;

  float* ws = (float*)d_ws;
  size_t off = 0;
  auto alloc = [&](size_t n) { float* p = ws + off; off += (n + 63) & ~(size_t)63; return p; };
  float* X      = alloc(256 * 832);
  float* gates  = alloc(256 * 2048);
  float* cbuf   = alloc(256 * 512);
  float* hbuf   = alloc(256 * 512);
  float* p_raw  = alloc(256 * 1072);
  float* kvec   = alloc(8 * 256 * 64);
  float* knorm  = alloc(8 * 256);
  float* betav  = alloc(8 * 256);
  float* gatev  = alloc(8 * 256);
  float* sv     = alloc(8 * 256 * 3);
  float* gammav = alloc(8 * 256);
  float* evec   = alloc(3 * 256 * 64);
  float* avec   = alloc(3 * 256 * 64);
  float* dot_a  = alloc((size_t)256 * 4096);
  float* dot_b  = alloc((size_t)256 * 4096);
  float* normr  = alloc((size_t)256 * 4096);
  float* w_all  = alloc((size_t)7 * 256 * 4096);
  float* reads  = alloc(4 * 256 * 64);
  float* state  = alloc(256 * 768);

  hipMemsetAsync(reads, 0, 4 * 256 * 64 * sizeof(float), stream);

  pack_x_kernel<<<(256 * 832 + 255) / 256, 256, 0, stream>>>(in_data, prev_r, h0, X);
  gemm_gates_kernel<<<dim3(32, 8), 256, 0, stream>>>(X, W_ih, W_hh, b_ih, b_hh, gates);
  lstm_elem_kernel<<<(256 * 512 + 255) / 256, 256, 0, stream>>>(gates, c0, cbuf, hbuf);
  gemm_heads_kernel<<<dim3(17, 8), 256, 0, stream>>>(cbuf, W_addr, W_ea, b_addr, b_ea, p_raw);
  head_params_kernel<<<dim3(8, 256), 128, 0, stream>>>(p_raw, kvec, knorm, betav, gatev, sv, gammav, evec, avec);

  dim3 pgrid(16, 256);
  // Pass A: dot0,dot1,||mem0||
  pass_kernel<0, 2, 0><<<pgrid, 256, 0, stream>>>(memory, kvec, 0, 1, w_all, evec, avec, 0,
                                                  dot_a, dot_b, normr, reads);
  chain_kernel<<<dim3(2, 256), 256, 0, stream>>>(dot_a, dot_b, normr, knorm, betav, gatev, sv, gammav, prev_w, w_all, 0);
  // Pass B: mem1 in regs; dot2,dot3,||mem1||; read0 from mem0
  pass_kernel<1, 2, 1><<<pgrid, 256, 0, stream>>>(memory, kvec, 2, 3, w_all, evec, avec, 0,
                                                  dot_a, dot_b, normr, reads + 0 * 256 * 64);
  chain_kernel<<<dim3(2, 256), 256, 0, stream>>>(dot_a, dot_b, normr, knorm, betav, gatev, sv, gammav, prev_w, w_all, 2);
  // Pass C: mem2 in regs; dot4,dot5,||mem2||; read2 from mem1
  pass_kernel<2, 2, 1><<<pgrid, 256, 0, stream>>>(memory, kvec, 4, 5, w_all, evec, avec, 2,
                                                  dot_a, dot_b, normr, reads + 1 * 256 * 64);
  chain_kernel<<<dim3(2, 256), 256, 0, stream>>>(dot_a, dot_b, normr, knorm, betav, gatev, sv, gammav, prev_w, w_all, 4);
  // Pass D: mem3 in regs; dot6,||mem3||; read4 from mem2
  pass_kernel<3, 1, 1><<<pgrid, 256, 0, stream>>>(memory, kvec, 6, 6, w_all, evec, avec, 4,
                                                  dot_a, dot_b, normr, reads + 2 * 256 * 64);
  chain_kernel<<<dim3(1, 256), 256, 0, stream>>>(dot_a, dot_b, normr, knorm, betav, gatev, sv, gammav, prev_w, w_all, 6);
  // Pass E: read6 from mem3 (final write head 7 is dead code — mem is not an output)
  pass_kernel<3, 0, 2><<<pgrid, 256, 0, stream>>>(memory, kvec, 0, 0, w_all, evec, avec, 6,
                                                  dot_a, dot_b, normr, reads + 3 * 256 * 64);

  pack_state_kernel<<<(256 * 768 + 255) / 256, 256, 0, stream>>>(hbuf, reads, state);
  gemm_out_kernel<<<dim3(1, 8), 256, 0, stream>>>(state, W_out, b_out, out);
}